// Round 2
// baseline (781.346 us; speedup 1.0000x reference)
//
#include <hip/hip_runtime.h>

// KNN argmin over L2 distances, round 2: SGPR-broadcast inner loop.
//
// d2[q][s] = |q|^2 + |s|^2 - 2 q.s ; argmin_s is invariant to |q|^2, so the
// comparison key is  key(s) = |s|^2 - 2 q.s.
//
// Layout: each LANE owns one query (its 64 dims held in 64 VGPRs, loaded
// coalesced from a transposed Q_T). Supports are wave-uniform: streamed
// through SCALAR loads (row-major S, base depends only on blockIdx/loop
// counter), so the inner loop is pure v_fmac_f32 (VGPR q, SGPR s) with no
// LDS traffic at all. R1 was LDS-BW-bound at 103 B/cyc/CU; this removes
// that pipe from the loop.
//
// Tie-break fidelity: reference argmin picks the FIRST minimal index.
// Strict < updates while scanning supports in ascending order (within
// group, across groups, across splits in k_select) keep the first minimum.

#define NTOT   16384
#define DIM    64
#define NSPLIT 16
#define SPB    (NTOT / NSPLIT)   // supports per k_argmin block: 1024
#define FLT_BIG 3.4e38f

// ---------------------------------------------------------------------------
// Transpose [nrows][64] -> [64][nrows]. block = 256 (64 x 4), grid = nrows/64.
__global__ __launch_bounds__(256) void k_transpose(
    const float* __restrict__ in, float* __restrict__ outT) {
  __shared__ float tile[64][65];  // +1 pad: conflict-free transposed reads
  const int tx = threadIdx.x & 63;
  const int ty = threadIdx.x >> 6;
  const int rbase = blockIdx.x * 64;
#pragma unroll
  for (int i = 0; i < 16; ++i) {
    const int r = i * 4 + ty;
    tile[r][tx] = in[(rbase + r) * DIM + tx];  // coalesced
  }
  __syncthreads();
#pragma unroll
  for (int i = 0; i < 16; ++i) {
    const int d = i * 4 + ty;
    outT[d * NTOT + rbase + tx] = tile[tx][d];  // coalesced, conflict-free
  }
}

// ---------------------------------------------------------------------------
// Per-row sum of squares for S. One thread per row; rows are L1/L2 resident
// (4 MB total), each 64B line is fully consumed across the j-loop.
__global__ __launch_bounds__(256) void k_rowsq(
    const float* __restrict__ in, float* __restrict__ sq) {
  const int r = blockIdx.x * 256 + threadIdx.x;
  const float4* row = (const float4*)(in + (size_t)r * DIM);
  float s = 0.0f;
#pragma unroll
  for (int j = 0; j < 16; ++j) {
    const float4 v = row[j];
    s = fmaf(v.x, v.x, s);
    s = fmaf(v.y, v.y, s);
    s = fmaf(v.z, v.z, s);
    s = fmaf(v.w, v.w, s);
  }
  sq[r] = s;
}

// ---------------------------------------------------------------------------
// Main kernel: lane q = blockIdx.x*256 + tid owns one query; block scans
// SPB supports of split blockIdx.y. grid = (NTOT/256, NSPLIT), block = 256.
__global__ __launch_bounds__(256) void k_argmin(
    const float* __restrict__ S,      // row-major [NTOT][64]
    const float* __restrict__ Q_T,    // [64][NTOT]
    const float* __restrict__ sqS,    // [NTOT]
    float* __restrict__ cand_key, int* __restrict__ cand_idx) {
  const int q = blockIdx.x * 256 + threadIdx.x;
  const int sbase = blockIdx.y * SPB;

  // Whole query in registers (64 VGPRs), coalesced b32 loads from Q_T.
  float qv[DIM];
#pragma unroll
  for (int d = 0; d < DIM; ++d) qv[d] = Q_T[d * NTOT + q];

  float best = FLT_BIG;
  int bix = 0;

  for (int g = 0; g < SPB; g += 4) {
    const int s0 = sbase + g;
    // Wave-uniform base: scalar loads (s_load) feed the FMAs directly.
    const float* __restrict__ srow = S + (size_t)s0 * DIM;
    float a0 = 0.f, a1 = 0.f, a2 = 0.f, a3 = 0.f;
#pragma unroll
    for (int d = 0; d < DIM; ++d) {
      const float qd = qv[d];
      a0 = fmaf(qd, srow[d], a0);
      a1 = fmaf(qd, srow[d + DIM], a1);
      a2 = fmaf(qd, srow[d + 2 * DIM], a2);
      a3 = fmaf(qd, srow[d + 3 * DIM], a3);
    }
    // key = |s|^2 - 2 q.s  (|q|^2 dropped: constant per lane).
    const float k0 = fmaf(-2.f, a0, sqS[s0]);
    const float k1 = fmaf(-2.f, a1, sqS[s0 + 1]);
    const float k2 = fmaf(-2.f, a2, sqS[s0 + 2]);
    const float k3 = fmaf(-2.f, a3, sqS[s0 + 3]);
    // Ascending index, strict < => first minimum wins (np.argmin).
    bool u;
    u = k0 < best; best = u ? k0 : best; bix = u ? (s0)     : bix;
    u = k1 < best; best = u ? k1 : best; bix = u ? (s0 + 1) : bix;
    u = k2 < best; best = u ? k2 : best; bix = u ? (s0 + 2) : bix;
    u = k3 < best; best = u ? k3 : best; bix = u ? (s0 + 3) : bix;
  }

  cand_key[blockIdx.y * NTOT + q] = best;
  cand_idx[blockIdx.y * NTOT + q] = bix;
}

// ---------------------------------------------------------------------------
// Reduce splits (ascending => strict < keeps lowest support index on ties),
// then label = argmax (first max) of the winning support's onehot row.
__global__ __launch_bounds__(256) void k_select(
    const float* __restrict__ cand_key, const int* __restrict__ cand_idx,
    const float* __restrict__ onehot, int* __restrict__ labels_pred) {
  const int q = blockIdx.x * 256 + threadIdx.x;
  float bd = cand_key[q];
  int bi = cand_idx[q];
#pragma unroll
  for (int s = 1; s < NSPLIT; ++s) {
    const float d = cand_key[s * NTOT + q];
    const int ix = cand_idx[s * NTOT + q];
    const bool u = d < bd;
    bd = u ? d : bd;
    bi = u ? ix : bi;
  }
  float mv = onehot[bi * 64];
  int mc = 0;
#pragma unroll
  for (int c = 1; c < 64; ++c) {
    const float v = onehot[bi * 64 + c];
    const bool u = v > mv;  // strict > => first max, matches np.argmax
    mv = u ? v : mv;
    mc = u ? c : mc;
  }
  labels_pred[q] = mc;
}

// ---------------------------------------------------------------------------
__global__ __launch_bounds__(256) void k_writeout(
    const int* __restrict__ labels_pred, float* __restrict__ out) {
  const int t = blockIdx.x * 256 + threadIdx.x;  // NTOT*64 total
  const int q = t >> 6;
  const int c = t & 63;
  out[t] = (c == labels_pred[q]) ? 1.0f : 0.0f;
}

// ---------------------------------------------------------------------------
extern "C" void kernel_launch(void* const* d_in, const int* in_sizes, int n_in,
                              void* d_out, int out_size, void* d_ws, size_t ws_size,
                              hipStream_t stream) {
  const float* S = (const float*)d_in[0];   // support_embeddings [16384][64]
  const float* Q = (const float*)d_in[1];   // query_embeddings   [16384][64]
  const float* OH = (const float*)d_in[2];  // support_labels_onehot [16384][64]
  float* out = (float*)d_out;               // [16384][64] fp32

  char* ws = (char*)d_ws;
  float* Q_T = (float*)ws;                                  // 4 MB
  float* sqS = (float*)(ws + (4u << 20));                   // 64 KB
  float* ckey = (float*)(ws + (4u << 20) + (64u << 10));    // 1 MB
  int* cix = (int*)(ws + (5u << 20) + (64u << 10));         // 1 MB
  int* lp = (int*)(ws + (6u << 20) + (64u << 10));          // 64 KB

  k_transpose<<<dim3(NTOT / 64), 256, 0, stream>>>(Q, Q_T);
  k_rowsq<<<dim3(NTOT / 256), 256, 0, stream>>>(S, sqS);
  k_argmin<<<dim3(NTOT / 256, NSPLIT), 256, 0, stream>>>(S, Q_T, sqS, ckey, cix);
  k_select<<<dim3(NTOT / 256), 256, 0, stream>>>(ckey, cix, OH, lp);
  k_writeout<<<dim3(NTOT * 64 / 256), 256, 0, stream>>>(lp, out);
  (void)in_sizes; (void)n_in; (void)out_size; (void)ws_size;
}

// Round 3
// 492.592 us; speedup vs baseline: 1.5862x; 1.5862x over previous
//
#include <hip/hip_runtime.h>

// KNN argmin over L2 distances, round 3: back to LDS tiling (R1 structure)
// but with 1.5 B/FMA instead of 2.0, conflict-free reads, and 4 blocks/CU.
//
// key(s) = |s|^2 - 2 q.s  (|q|^2 dropped: constant per query, argmin-invariant)
//
// Block: 256 threads = 16 tx (4 queries each) x 16 ty (8 supports each).
// Tile: 64 queries x 128 supports per chunk; SPB=2048 supports per block.
// sQ[64k][64q] (16 KB, staged once) + sS[32k][128s] (16 KB, staged per k-half)
// = 33 KB LDS -> 4 blocks/CU (16 waves/CU). Grid 2048 blocks = 2.0 rounds.
//
// Tie-break: reference argmin takes the FIRST minimal index. Within-thread
// scans are ascending-index with strict <. Cross-thread/cross-split
// reductions use lexicographic (key, idx) compare since support sets
// interleave; identical keys are bitwise-deterministic (same fmaf sequence).

#define NTOT   16384
#define DIM    64
#define NSPLIT 8
#define SPB    (NTOT / NSPLIT)   // 2048 supports per block
#define CHUNK  128
#define FLT_BIG 3.4e38f

// ---------------------------------------------------------------------------
// Transpose [nrows][64] -> [64][nrows] (+ optional row sum of squares).
__global__ __launch_bounds__(256) void k_transpose_sq(
    const float* __restrict__ in, float* __restrict__ outT,
    float* __restrict__ sq) {
  __shared__ float tile[64][65];
  const int tx = threadIdx.x & 63;
  const int ty = threadIdx.x >> 6;
  const int rbase = blockIdx.x * 64;
#pragma unroll
  for (int i = 0; i < 16; ++i) {
    const int r = i * 4 + ty;
    tile[r][tx] = in[(rbase + r) * DIM + tx];
  }
  __syncthreads();
#pragma unroll
  for (int i = 0; i < 16; ++i) {
    const int d = i * 4 + ty;
    outT[d * NTOT + rbase + tx] = tile[tx][d];
  }
  if (sq != nullptr && threadIdx.x < 64) {
    float s = 0.0f;
#pragma unroll
    for (int d = 0; d < DIM; ++d) {
      const float v = tile[threadIdx.x][d];
      s = fmaf(v, v, s);
    }
    sq[rbase + threadIdx.x] = s;
  }
}

// ---------------------------------------------------------------------------
__global__ __launch_bounds__(256, 4) void k_argmin(
    const float* __restrict__ S_T,    // [64][NTOT]
    const float* __restrict__ Q_T,    // [64][NTOT]
    const float* __restrict__ sqS,    // [NTOT]
    float* __restrict__ cand_key, int* __restrict__ cand_idx) {
  __shared__ __align__(16) float sQ[64 * 64];    // [k][q] 16 KB
  __shared__ __align__(16) float sS[32 * 128];   // [k][s] 16 KB (one k-half)
  __shared__ float sqs_sh[128];

  const int tid = threadIdx.x;
  const int tx = tid & 15;   // query group: queries qbase + tx*4 .. +3
  const int ty = tid >> 4;   // support group: chunk supports ty*8 .. +7
  const int qbase = blockIdx.x * 64;
  const int sbase0 = blockIdx.y * SPB;

  // Stage sQ once: [k][q] from Q_T. Coalesced: each instr reads 16 rows
  // x 256B; LDS writes contiguous 1KB/wave.
#pragma unroll
  for (int i = 0; i < 4; ++i) {
    const int j = tid + i * 256;          // float4 index over [64][16]
    const int r = j >> 4;
    const int c = (j & 15) << 2;
    *(float4*)&sQ[r * 64 + c] = *(const float4*)&Q_T[r * NTOT + qbase + c];
  }

  float best[4] = {FLT_BIG, FLT_BIG, FLT_BIG, FLT_BIG};
  int bix[4] = {0, 0, 0, 0};

  for (int chunk = 0; chunk < SPB / CHUNK; ++chunk) {
    const int sb = sbase0 + chunk * CHUNK;
    float acc[4][8];
#pragma unroll
    for (int i = 0; i < 4; ++i)
#pragma unroll
      for (int j = 0; j < 8; ++j) acc[i][j] = 0.0f;

#pragma unroll
    for (int kh = 0; kh < 2; ++kh) {
      __syncthreads();  // readers of previous sS contents are done
#pragma unroll
      for (int i = 0; i < 4; ++i) {
        const int j = tid + i * 256;      // float4 index over [32][32]
        const int r = j >> 5;
        const int c = (j & 31) << 2;
        *(float4*)&sS[r * 128 + c] =
            *(const float4*)&S_T[(kh * 32 + r) * NTOT + sb + c];
      }
      if (kh == 0 && tid < 128) sqs_sh[tid] = sqS[sb + tid];
      __syncthreads();

#pragma unroll 8
      for (int k = 0; k < 32; ++k) {
        // sQ read: 16 distinct 16B addrs, 2-way bank alias (free) + 4x bcast
        const float4 qv = *(const float4*)&sQ[(kh * 32 + k) * 64 + tx * 4];
        // sS reads: 4 distinct addrs per wave, conflict-free, 16x bcast
        const float4 sv0 = *(const float4*)&sS[k * 128 + ty * 8];
        const float4 sv1 = *(const float4*)&sS[k * 128 + ty * 8 + 4];
        const float q0 = qv.x, q1 = qv.y, q2 = qv.z, q3 = qv.w;
        acc[0][0] = fmaf(q0, sv0.x, acc[0][0]);
        acc[0][1] = fmaf(q0, sv0.y, acc[0][1]);
        acc[0][2] = fmaf(q0, sv0.z, acc[0][2]);
        acc[0][3] = fmaf(q0, sv0.w, acc[0][3]);
        acc[0][4] = fmaf(q0, sv1.x, acc[0][4]);
        acc[0][5] = fmaf(q0, sv1.y, acc[0][5]);
        acc[0][6] = fmaf(q0, sv1.z, acc[0][6]);
        acc[0][7] = fmaf(q0, sv1.w, acc[0][7]);
        acc[1][0] = fmaf(q1, sv0.x, acc[1][0]);
        acc[1][1] = fmaf(q1, sv0.y, acc[1][1]);
        acc[1][2] = fmaf(q1, sv0.z, acc[1][2]);
        acc[1][3] = fmaf(q1, sv0.w, acc[1][3]);
        acc[1][4] = fmaf(q1, sv1.x, acc[1][4]);
        acc[1][5] = fmaf(q1, sv1.y, acc[1][5]);
        acc[1][6] = fmaf(q1, sv1.z, acc[1][6]);
        acc[1][7] = fmaf(q1, sv1.w, acc[1][7]);
        acc[2][0] = fmaf(q2, sv0.x, acc[2][0]);
        acc[2][1] = fmaf(q2, sv0.y, acc[2][1]);
        acc[2][2] = fmaf(q2, sv0.z, acc[2][2]);
        acc[2][3] = fmaf(q2, sv0.w, acc[2][3]);
        acc[2][4] = fmaf(q2, sv1.x, acc[2][4]);
        acc[2][5] = fmaf(q2, sv1.y, acc[2][5]);
        acc[2][6] = fmaf(q2, sv1.z, acc[2][6]);
        acc[2][7] = fmaf(q2, sv1.w, acc[2][7]);
        acc[3][0] = fmaf(q3, sv0.x, acc[3][0]);
        acc[3][1] = fmaf(q3, sv0.y, acc[3][1]);
        acc[3][2] = fmaf(q3, sv0.z, acc[3][2]);
        acc[3][3] = fmaf(q3, sv0.w, acc[3][3]);
        acc[3][4] = fmaf(q3, sv1.x, acc[3][4]);
        acc[3][5] = fmaf(q3, sv1.y, acc[3][5]);
        acc[3][6] = fmaf(q3, sv1.z, acc[3][6]);
        acc[3][7] = fmaf(q3, sv1.w, acc[3][7]);
      }
    }

    // Epilogue: ascending support index within thread; strict < keeps the
    // first minimum (np.argmin semantics).
#pragma unroll
    for (int j = 0; j < 8; ++j) {
      const float sq_j = sqs_sh[ty * 8 + j];
      const int sidx = sb + ty * 8 + j;
#pragma unroll
      for (int i = 0; i < 4; ++i) {
        const float key = fmaf(-2.0f, acc[i][j], sq_j);
        const bool u = key < best[i];
        best[i] = u ? key : best[i];
        bix[i] = u ? sidx : bix[i];
      }
    }
  }

  // Cross-ty reduction: support sets of different ty interleave across
  // chunks, so use lexicographic (key, idx) compare. Reuse sS (16 KB).
  __syncthreads();
  float* const red_k = sS;                       // [64][17] padded
  int* const red_i = (int*)(sS + 64 * 17);       // [64][17]
#pragma unroll
  for (int i = 0; i < 4; ++i) {
    const int q = tx * 4 + i;
    red_k[q * 17 + ty] = best[i];
    red_i[q * 17 + ty] = bix[i];
  }
  __syncthreads();
  if (tid < 64) {
    float bk = red_k[tid * 17];
    int bi = red_i[tid * 17];
#pragma unroll
    for (int t = 1; t < 16; ++t) {
      const float d = red_k[tid * 17 + t];
      const int ix = red_i[tid * 17 + t];
      const bool u = (d < bk) || (d == bk && ix < bi);
      bk = u ? d : bk;
      bi = u ? ix : bi;
    }
    cand_key[blockIdx.y * NTOT + qbase + tid] = bk;
    cand_idx[blockIdx.y * NTOT + qbase + tid] = bi;
  }
}

// ---------------------------------------------------------------------------
// Reduce splits (lexicographic), then label = first-argmax of onehot row.
__global__ __launch_bounds__(256) void k_select(
    const float* __restrict__ cand_key, const int* __restrict__ cand_idx,
    const float* __restrict__ onehot, int* __restrict__ labels_pred) {
  const int q = blockIdx.x * 256 + threadIdx.x;
  float bd = cand_key[q];
  int bi = cand_idx[q];
#pragma unroll
  for (int s = 1; s < NSPLIT; ++s) {
    const float d = cand_key[s * NTOT + q];
    const int ix = cand_idx[s * NTOT + q];
    const bool u = (d < bd) || (d == bd && ix < bi);
    bd = u ? d : bd;
    bi = u ? ix : bi;
  }
  float mv = onehot[bi * 64];
  int mc = 0;
#pragma unroll
  for (int c = 1; c < 64; ++c) {
    const float v = onehot[bi * 64 + c];
    const bool u = v > mv;  // strict > => first max, matches np.argmax
    mv = u ? v : mv;
    mc = u ? c : mc;
  }
  labels_pred[q] = mc;
}

// ---------------------------------------------------------------------------
__global__ __launch_bounds__(256) void k_writeout(
    const int* __restrict__ labels_pred, float* __restrict__ out) {
  const int t = blockIdx.x * 256 + threadIdx.x;  // NTOT*64 total
  const int q = t >> 6;
  const int c = t & 63;
  out[t] = (c == labels_pred[q]) ? 1.0f : 0.0f;
}

// ---------------------------------------------------------------------------
extern "C" void kernel_launch(void* const* d_in, const int* in_sizes, int n_in,
                              void* d_out, int out_size, void* d_ws, size_t ws_size,
                              hipStream_t stream) {
  const float* S = (const float*)d_in[0];   // support_embeddings [16384][64]
  const float* Q = (const float*)d_in[1];   // query_embeddings   [16384][64]
  const float* OH = (const float*)d_in[2];  // support_labels_onehot [16384][64]
  float* out = (float*)d_out;               // [16384][64] fp32

  char* ws = (char*)d_ws;
  float* S_T = (float*)ws;                                   // 4 MB
  float* Q_T = (float*)(ws + (4u << 20));                    // 4 MB
  float* sqS = (float*)(ws + (8u << 20));                    // 64 KB
  float* ckey = (float*)(ws + (8u << 20) + (64u << 10));     // 512 KB
  int* cix = (int*)(ws + (8u << 20) + (576u << 10));         // 512 KB
  int* lp = (int*)(ws + (9u << 20) + (64u << 10));           // 64 KB

  k_transpose_sq<<<dim3(NTOT / 64), 256, 0, stream>>>(S, S_T, sqS);
  k_transpose_sq<<<dim3(NTOT / 64), 256, 0, stream>>>(Q, Q_T, nullptr);
  k_argmin<<<dim3(NTOT / 64, NSPLIT), 256, 0, stream>>>(S_T, Q_T, sqS, ckey, cix);
  k_select<<<dim3(NTOT / 256), 256, 0, stream>>>(ckey, cix, OH, lp);
  k_writeout<<<dim3(NTOT * 64 / 256), 256, 0, stream>>>(lp, out);
  (void)in_sizes; (void)n_in; (void)out_size; (void)ws_size;
}

// Round 4
// 464.115 us; speedup vs baseline: 1.6835x; 1.0614x over previous
//
#include <hip/hip_runtime.h>

// KNN argmin over L2, round 4: bf16-split MFMA filter + exact fp32 rescore.
//
// key(s) = |s|^2 - 2 q.s  (|q|^2 argmin-invariant).
// Split x = hi + lo (both bf16, RNE):  |x - (hi+lo)| <= 2^-18 |x|.
// Approx cross = s_hi.q_hi + s_lo.q_hi + s_hi.q_lo  via MFMA; neglected terms
// bound the key error by ~3e-3 << EPS=0.02.
//
// Phase A (MFMA, no LDS): per (query, 256-support block) approximate key min.
//   A = supports (M), B = queries (N), 16x16x32 bf16 MFMA.
//   A frag: lane l holds A[m=l&15][k=(l>>4)*8+j] -> 16B contiguous from
//   row-major S_hi/S_lo.  B frag: B[k=(l>>4)*8+j][n=l&15] = Q[n][k] -> 16B
//   contiguous from row-major Q_hi/Q_lo.  C/D: col(n)=l&15, row(m)=(l>>4)*4+r.
// Phase B (exact): per query, evaluate in fp32 every 256-block whose approx
//   min <= global approx min + EPS. The first-argmin block is provably
//   included; skipped supports are provably worse. Strict-< ascending scan +
//   lexicographic cross-lane reduce reproduces np.argmin first-index
//   semantics (fp32-ordering noise ~1e-6 was empirically flip-free in R1/R3).

#define NTOT   16384
#define DIM    64
#define NSPLIT 32
#define SPB    (NTOT / NSPLIT)    // 512 supports per phase-A wave
#define STEPS  (SPB / 16)         // 32
#define SBLK   256                // bmin granularity
#define NSB    (NTOT / SBLK)      // 64
#define EPS    0.02f
#define FLT_BIG 3.4e38f

typedef __attribute__((ext_vector_type(8))) short short8;
typedef __attribute__((ext_vector_type(4))) float float4v;

__device__ __forceinline__ ushort bf16_rne(float x) {
  unsigned u = __float_as_uint(x);
  return (ushort)((u + 0x7FFF + ((u >> 16) & 1)) >> 16);
}

// ---------------------------------------------------------------------------
// Split S and Q into (hi, lo) bf16 arrays, row-major [n][64].
__global__ __launch_bounds__(256) void k_split(
    const float* __restrict__ S, const float* __restrict__ Q,
    ushort* __restrict__ Sh, ushort* __restrict__ Sl,
    ushort* __restrict__ Qh, ushort* __restrict__ Ql) {
  const int t = blockIdx.x * 256 + threadIdx.x;  // over 32768 rows x 16 f4
  const int row = t >> 4;
  const int c4 = (t & 15) << 2;
  const bool isS = row < NTOT;
  const int r = isS ? row : row - NTOT;
  const float4 v = *(const float4*)&(isS ? S : Q)[(size_t)r * DIM + c4];
  const float f[4] = {v.x, v.y, v.z, v.w};
  ushort h[4], l[4];
#pragma unroll
  for (int i = 0; i < 4; ++i) {
    h[i] = bf16_rne(f[i]);
    const float hf = __uint_as_float(((unsigned)h[i]) << 16);
    l[i] = bf16_rne(f[i] - hf);
  }
  ushort* dh = isS ? Sh : Qh;
  ushort* dl = isS ? Sl : Ql;
  *(ushort4*)&dh[(size_t)r * DIM + c4] = make_ushort4(h[0], h[1], h[2], h[3]);
  *(ushort4*)&dl[(size_t)r * DIM + c4] = make_ushort4(l[0], l[1], l[2], l[3]);
}

// ---------------------------------------------------------------------------
__global__ __launch_bounds__(256) void k_rowsq(
    const float* __restrict__ in, float* __restrict__ sq) {
  const int r = blockIdx.x * 256 + threadIdx.x;
  const float4* row = (const float4*)(in + (size_t)r * DIM);
  float s = 0.0f;
#pragma unroll
  for (int j = 0; j < 16; ++j) {
    const float4 v = row[j];
    s = fmaf(v.x, v.x, s);
    s = fmaf(v.y, v.y, s);
    s = fmaf(v.z, v.z, s);
    s = fmaf(v.w, v.w, s);
  }
  sq[r] = s;
}

// ---------------------------------------------------------------------------
// Phase A: one wave per (64 queries, 512 supports). grid=(256, NSPLIT).
__global__ __launch_bounds__(64, 3) void k_phaseA(
    const ushort* __restrict__ Sh, const ushort* __restrict__ Sl,
    const ushort* __restrict__ Qh, const ushort* __restrict__ Ql,
    const float* __restrict__ sqS, float* __restrict__ bmin) {
  const int l = threadIdx.x;
  const int lm = l & 15;
  const int lq = l >> 4;
  const int qbase = blockIdx.x * 64;
  const int sbase = blockIdx.y * SPB;

  // Query (B) fragments for 4 tiles x 2 k-chunks, hi and lo. 64 VGPRs.
  short8 qh[4][2], qlo[4][2];
#pragma unroll
  for (int t = 0; t < 4; ++t) {
    const size_t rq = (size_t)(qbase + t * 16 + lm) * DIM + lq * 8;
#pragma unroll
    for (int kc = 0; kc < 2; ++kc) {
      qh[t][kc]  = *(const short8*)&Qh[rq + kc * 32];
      qlo[t][kc] = *(const short8*)&Ql[rq + kc * 32];
    }
  }

  const size_t aoff = (size_t)lm * DIM + lq * 8;  // lane offset in 16-row panel
  float bmr[4] = {FLT_BIG, FLT_BIG, FLT_BIG, FLT_BIG};

  for (int st = 0; st < STEPS; ++st) {
    const size_t sr = (size_t)(sbase + st * 16) * DIM + aoff;
    const short8 ah0 = *(const short8*)&Sh[sr];
    const short8 ah1 = *(const short8*)&Sh[sr + 32];
    const short8 al0 = *(const short8*)&Sl[sr];
    const short8 al1 = *(const short8*)&Sl[sr + 32];
    const float4 sq4 = *(const float4*)&sqS[sbase + st * 16 + lq * 4];
#pragma unroll
    for (int t = 0; t < 4; ++t) {
      float4v acc = {0.f, 0.f, 0.f, 0.f};
      acc = __builtin_amdgcn_mfma_f32_16x16x32_bf16(ah0, qh[t][0], acc, 0, 0, 0);
      acc = __builtin_amdgcn_mfma_f32_16x16x32_bf16(ah1, qh[t][1], acc, 0, 0, 0);
      acc = __builtin_amdgcn_mfma_f32_16x16x32_bf16(al0, qh[t][0], acc, 0, 0, 0);
      acc = __builtin_amdgcn_mfma_f32_16x16x32_bf16(al1, qh[t][1], acc, 0, 0, 0);
      acc = __builtin_amdgcn_mfma_f32_16x16x32_bf16(ah0, qlo[t][0], acc, 0, 0, 0);
      acc = __builtin_amdgcn_mfma_f32_16x16x32_bf16(ah1, qlo[t][1], acc, 0, 0, 0);
      const float k0 = fmaf(-2.f, acc[0], sq4.x);
      const float k1 = fmaf(-2.f, acc[1], sq4.y);
      const float k2 = fmaf(-2.f, acc[2], sq4.z);
      const float k3 = fmaf(-2.f, acc[3], sq4.w);
      bmr[t] = fminf(bmr[t], fminf(fminf(k0, k1), fminf(k2, k3)));
    }
    if ((st & 15) == 15) {  // finished a 256-support block
      const int gb = blockIdx.y * (SPB / SBLK) + (st >> 4);
#pragma unroll
      for (int t = 0; t < 4; ++t) {
        float v = bmr[t];
        v = fminf(v, __shfl_xor(v, 16, 64));
        v = fminf(v, __shfl_xor(v, 32, 64));
        if (lq == 0) bmin[(size_t)(qbase + t * 16 + lm) * NSB + gb] = v;
        bmr[t] = FLT_BIG;
      }
    }
  }
}

// ---------------------------------------------------------------------------
// Phase B: one wave per query. grid = NTOT/4 blocks of 256.
__global__ __launch_bounds__(256) void k_phaseB(
    const float* __restrict__ S, const float* __restrict__ Q,
    const float* __restrict__ sqS, const float* __restrict__ bmin,
    const float* __restrict__ onehot, float* __restrict__ out) {
  const int lane = threadIdx.x & 63;
  const int q = blockIdx.x * 4 + (threadIdx.x >> 6);

  const float bv = bmin[(size_t)q * NSB + lane];  // lane <-> block (NSB==64)
  float m = bv;
#pragma unroll
  for (int d = 1; d < 64; d <<= 1) m = fminf(m, __shfl_xor(m, d, 64));
  const float thr = m + EPS;

  const float4* q4p = (const float4*)&Q[(size_t)q * DIM];

  float bk = FLT_BIG;
  int bi = 0;
  for (int b = 0; b < NSB; ++b) {
    if (__shfl(bv, b, 64) <= thr) {  // wave-uniform
      const int s0 = b * SBLK + lane * 4;
      const float4* r0 = (const float4*)&S[(size_t)s0 * DIM];
      const float4* r1 = (const float4*)&S[(size_t)(s0 + 1) * DIM];
      const float4* r2 = (const float4*)&S[(size_t)(s0 + 2) * DIM];
      const float4* r3 = (const float4*)&S[(size_t)(s0 + 3) * DIM];
      float a0 = 0.f, a1 = 0.f, a2 = 0.f, a3 = 0.f;
#pragma unroll
      for (int k4 = 0; k4 < 16; ++k4) {
        const float4 qv = q4p[k4];
        const float4 v0 = r0[k4];
        const float4 v1 = r1[k4];
        const float4 v2 = r2[k4];
        const float4 v3 = r3[k4];
        a0 = fmaf(qv.x, v0.x, a0); a0 = fmaf(qv.y, v0.y, a0);
        a0 = fmaf(qv.z, v0.z, a0); a0 = fmaf(qv.w, v0.w, a0);
        a1 = fmaf(qv.x, v1.x, a1); a1 = fmaf(qv.y, v1.y, a1);
        a1 = fmaf(qv.z, v1.z, a1); a1 = fmaf(qv.w, v1.w, a1);
        a2 = fmaf(qv.x, v2.x, a2); a2 = fmaf(qv.y, v2.y, a2);
        a2 = fmaf(qv.z, v2.z, a2); a2 = fmaf(qv.w, v2.w, a2);
        a3 = fmaf(qv.x, v3.x, a3); a3 = fmaf(qv.y, v3.y, a3);
        a3 = fmaf(qv.z, v3.z, a3); a3 = fmaf(qv.w, v3.w, a3);
      }
      const float4 sq4 = *(const float4*)&sqS[s0];
      const float k0 = fmaf(-2.f, a0, sq4.x);
      const float k1 = fmaf(-2.f, a1, sq4.y);
      const float k2 = fmaf(-2.f, a2, sq4.z);
      const float k3 = fmaf(-2.f, a3, sq4.w);
      bool u;  // ascending index, strict < => first minimum per lane
      u = k0 < bk; bk = u ? k0 : bk; bi = u ? s0 : bi;
      u = k1 < bk; bk = u ? k1 : bk; bi = u ? (s0 + 1) : bi;
      u = k2 < bk; bk = u ? k2 : bk; bi = u ? (s0 + 2) : bi;
      u = k3 < bk; bk = u ? k3 : bk; bi = u ? (s0 + 3) : bi;
    }
  }
  // Cross-lane lexicographic argmin: exact keys => first-index semantics.
#pragma unroll
  for (int d = 1; d < 64; d <<= 1) {
    const float ok = __shfl_xor(bk, d, 64);
    const int oi = __shfl_xor(bi, d, 64);
    const bool u = (ok < bk) || (ok == bk && oi < bi);
    bk = u ? ok : bk;
    bi = u ? oi : bi;
  }
  // Label: one-hot rows are exact {0,1}; first (only) 1 == np.argmax.
  const float ov = onehot[(size_t)bi * 64 + lane];
  const unsigned long long msk = __ballot(ov > 0.5f);
  const int label = __ffsll(msk) - 1;
  out[(size_t)q * 64 + lane] = (lane == label) ? 1.0f : 0.0f;
}

// ---------------------------------------------------------------------------
extern "C" void kernel_launch(void* const* d_in, const int* in_sizes, int n_in,
                              void* d_out, int out_size, void* d_ws, size_t ws_size,
                              hipStream_t stream) {
  const float* S = (const float*)d_in[0];   // [16384][64]
  const float* Q = (const float*)d_in[1];   // [16384][64]
  const float* OH = (const float*)d_in[2];  // [16384][64]
  float* out = (float*)d_out;

  char* ws = (char*)d_ws;
  ushort* Sh = (ushort*)ws;                                  // 2 MB
  ushort* Sl = (ushort*)(ws + (2u << 20));                   // 2 MB
  ushort* Qh = (ushort*)(ws + (4u << 20));                   // 2 MB
  ushort* Ql = (ushort*)(ws + (6u << 20));                   // 2 MB
  float* sqS = (float*)(ws + (8u << 20));                    // 64 KB
  float* bmin = (float*)(ws + (8u << 20) + (64u << 10));     // 4 MB

  k_split<<<dim3(2048), 256, 0, stream>>>(S, Q, Sh, Sl, Qh, Ql);
  k_rowsq<<<dim3(NTOT / 256), 256, 0, stream>>>(S, sqS);
  k_phaseA<<<dim3(256, NSPLIT), 64, 0, stream>>>(Sh, Sl, Qh, Ql, sqS, bmin);
  k_phaseB<<<dim3(NTOT / 4), 256, 0, stream>>>(S, Q, sqS, bmin, OH, out);
  (void)in_sizes; (void)n_in; (void)out_size; (void)ws_size;
}

// Round 5
// 250.725 us; speedup vs baseline: 3.1163x; 1.8511x over previous
//
#include <hip/hip_runtime.h>

// KNN argmin over L2, round 5.
//   Phase A: hi-bf16 MFMA filter (1 term, EPS widened to 3.0), register
//            double-buffered A-panel loads, 4-wave blocks.
//   Phase B: coalesced exact fp32 rescore from transposed S_T (lane-stride
//            16B float4 loads), query row in LDS (broadcast), ballot-driven
//            candidate-block walk instead of a 64-iteration branch scan.
//
// key(s) = |s|^2 - 2 q.s  (|q|^2 argmin-invariant).
// Filter correctness: approx key error |Δkey| = 2|Δcross| <= 2 * 2^-8 *
// |q||s| <= ~1.1 for this data (|q|^2,|s|^2 <= ~140 at 16k-sample tails).
// Rescoring every block with bmin <= min(bmin) + EPS, EPS=3.0 >= 2*δ,
// provably includes the true first-argmin support (and any exact ties).
// Phase B compares exact fp32 keys with strict-< ascending scan +
// lexicographic cross-lane reduce => np.argmin first-index semantics.

#define NTOT   16384
#define DIM    64
#define SBLK   256                // bmin granularity
#define NSB    (NTOT / SBLK)      // 64
#define EPS    3.0f
#define FLT_BIG 3.4e38f

typedef __attribute__((ext_vector_type(8))) short short8;
typedef __attribute__((ext_vector_type(4))) float float4v;

__device__ __forceinline__ ushort bf16_rne(float x) {
  unsigned u = __float_as_uint(x);
  return (ushort)((u + 0x7FFF + ((u >> 16) & 1)) >> 16);
}

// ---------------------------------------------------------------------------
// Split S and Q to hi-bf16 row-major [n][64].
__global__ __launch_bounds__(256) void k_split(
    const float* __restrict__ S, const float* __restrict__ Q,
    ushort* __restrict__ Sh, ushort* __restrict__ Qh) {
  const int t = blockIdx.x * 256 + threadIdx.x;  // 32768 rows x 16 float4
  const int row = t >> 4;
  const int c4 = (t & 15) << 2;
  const bool isS = row < NTOT;
  const int r = isS ? row : row - NTOT;
  const float4 v = *(const float4*)&(isS ? S : Q)[(size_t)r * DIM + c4];
  ushort4 h = make_ushort4(bf16_rne(v.x), bf16_rne(v.y),
                           bf16_rne(v.z), bf16_rne(v.w));
  *(ushort4*)&(isS ? Sh : Qh)[(size_t)r * DIM + c4] = h;
}

// ---------------------------------------------------------------------------
// Transpose [nrows][64] -> [64][nrows] and per-row sum of squares.
__global__ __launch_bounds__(256) void k_transpose_sq(
    const float* __restrict__ in, float* __restrict__ outT,
    float* __restrict__ sq) {
  __shared__ float tile[64][65];
  const int tx = threadIdx.x & 63;
  const int ty = threadIdx.x >> 6;
  const int rbase = blockIdx.x * 64;
#pragma unroll
  for (int i = 0; i < 16; ++i) {
    const int r = i * 4 + ty;
    tile[r][tx] = in[(rbase + r) * DIM + tx];
  }
  __syncthreads();
#pragma unroll
  for (int i = 0; i < 16; ++i) {
    const int d = i * 4 + ty;
    outT[d * NTOT + rbase + tx] = tile[tx][d];
  }
  if (threadIdx.x < 64) {
    float s = 0.0f;
#pragma unroll
    for (int d = 0; d < DIM; ++d) {
      const float v = tile[threadIdx.x][d];
      s = fmaf(v, v, s);
    }
    sq[rbase + threadIdx.x] = s;
  }
}

// ---------------------------------------------------------------------------
// Phase A: block = 4 waves; wave w: 64 queries x 512 supports.
// grid = (NTOT/64, 8). A = supports (M), B = queries (N), 16x16x32 bf16.
// A frag: lane l holds A[m=l&15][k=(l>>4)*8+j]; B frag: B[k][n=l&15]=Q[n][k];
// C/D: col(n)=l&15, row(m)=(l>>4)*4+reg.  (Layouts HW-verified in R4.)
__global__ __launch_bounds__(256) void k_phaseA(
    const ushort* __restrict__ Sh, const ushort* __restrict__ Qh,
    const float* __restrict__ sqS, float* __restrict__ bmin) {
  const int tid = threadIdx.x;
  const int l = tid & 63;
  const int w = tid >> 6;
  const int lm = l & 15;
  const int lq = l >> 4;
  const int qbase = blockIdx.x * 64;
  const int sbase = blockIdx.y * 2048 + w * 512;

  // Query (B) fragments: 4 tiles x 2 k-chunks. 32 VGPRs.
  short8 qf[4][2];
#pragma unroll
  for (int t = 0; t < 4; ++t) {
    const size_t rq = (size_t)(qbase + t * 16 + lm) * DIM + lq * 8;
    qf[t][0] = *(const short8*)&Qh[rq];
    qf[t][1] = *(const short8*)&Qh[rq + 32];
  }

  const size_t aoff = (size_t)lm * DIM + lq * 8;
  // Prefetch step 0 (register double-buffer).
  short8 a0 = *(const short8*)&Sh[(size_t)sbase * DIM + aoff];
  short8 a1 = *(const short8*)&Sh[(size_t)sbase * DIM + aoff + 32];
  float4 sq4 = *(const float4*)&sqS[sbase + lq * 4];

  float bmr[4] = {FLT_BIG, FLT_BIG, FLT_BIG, FLT_BIG};

  for (int st = 0; st < 32; ++st) {
    const short8 ca0 = a0, ca1 = a1;
    const float4 csq = sq4;
    if (st < 31) {  // issue next step's loads before this step's MFMAs
      const size_t nr = (size_t)(sbase + (st + 1) * 16) * DIM + aoff;
      a0 = *(const short8*)&Sh[nr];
      a1 = *(const short8*)&Sh[nr + 32];
      sq4 = *(const float4*)&sqS[sbase + (st + 1) * 16 + lq * 4];
    }
#pragma unroll
    for (int t = 0; t < 4; ++t) {
      float4v acc = {0.f, 0.f, 0.f, 0.f};
      acc = __builtin_amdgcn_mfma_f32_16x16x32_bf16(ca0, qf[t][0], acc, 0, 0, 0);
      acc = __builtin_amdgcn_mfma_f32_16x16x32_bf16(ca1, qf[t][1], acc, 0, 0, 0);
      const float k0 = fmaf(-2.f, acc[0], csq.x);
      const float k1 = fmaf(-2.f, acc[1], csq.y);
      const float k2 = fmaf(-2.f, acc[2], csq.z);
      const float k3 = fmaf(-2.f, acc[3], csq.w);
      bmr[t] = fminf(bmr[t], fminf(fminf(k0, k1), fminf(k2, k3)));
    }
    if ((st & 15) == 15) {  // finished one 256-support block
      const int gb = blockIdx.y * 8 + w * 2 + (st >> 4);
#pragma unroll
      for (int t = 0; t < 4; ++t) {
        float v = bmr[t];
        v = fminf(v, __shfl_xor(v, 16, 64));
        v = fminf(v, __shfl_xor(v, 32, 64));
        if (lq == 0) bmin[(size_t)(qbase + t * 16 + lm) * NSB + gb] = v;
        bmr[t] = FLT_BIG;
      }
    }
  }
}

// ---------------------------------------------------------------------------
// Phase B: one wave per query; coalesced rescore from S_T.
__global__ __launch_bounds__(256) void k_phaseB(
    const float* __restrict__ S_T,   // [64][NTOT]
    const float* __restrict__ Q,     // [NTOT][64]
    const float* __restrict__ sqS, const float* __restrict__ bmin,
    const float* __restrict__ onehot, float* __restrict__ out) {
  __shared__ float sQrow[4][64];
  const int lane = threadIdx.x & 63;
  const int w = threadIdx.x >> 6;
  const int q = blockIdx.x * 4 + w;

  if (lane < 16)
    *(float4*)&sQrow[w][lane * 4] = *(const float4*)&Q[(size_t)q * DIM + lane * 4];
  __syncthreads();

  const float bv = bmin[(size_t)q * NSB + lane];  // lane <-> block
  float m = bv;
#pragma unroll
  for (int d = 1; d < 64; d <<= 1) m = fminf(m, __shfl_xor(m, d, 64));
  unsigned long long msk = __ballot(bv <= m + EPS);

  float bk = FLT_BIG;
  int bi = 0;
  while (msk) {  // ascending block order; wave-uniform control
    const int b = __ffsll((long long)msk) - 1;
    msk &= msk - 1;
    const int s0 = b * SBLK + lane * 4;  // 4 consecutive supports per lane
    float a0 = 0.f, a1 = 0.f, a2 = 0.f, a3 = 0.f;
#pragma unroll
    for (int c = 0; c < 16; ++c) {
      const float4 qv = *(const float4*)&sQrow[w][c * 4];  // LDS broadcast
      const float4 s0v = *(const float4*)&S_T[(size_t)(c * 4 + 0) * NTOT + s0];
      const float4 s1v = *(const float4*)&S_T[(size_t)(c * 4 + 1) * NTOT + s0];
      const float4 s2v = *(const float4*)&S_T[(size_t)(c * 4 + 2) * NTOT + s0];
      const float4 s3v = *(const float4*)&S_T[(size_t)(c * 4 + 3) * NTOT + s0];
      a0 = fmaf(qv.x, s0v.x, a0); a1 = fmaf(qv.x, s0v.y, a1);
      a2 = fmaf(qv.x, s0v.z, a2); a3 = fmaf(qv.x, s0v.w, a3);
      a0 = fmaf(qv.y, s1v.x, a0); a1 = fmaf(qv.y, s1v.y, a1);
      a2 = fmaf(qv.y, s1v.z, a2); a3 = fmaf(qv.y, s1v.w, a3);
      a0 = fmaf(qv.z, s2v.x, a0); a1 = fmaf(qv.z, s2v.y, a1);
      a2 = fmaf(qv.z, s2v.z, a2); a3 = fmaf(qv.z, s2v.w, a3);
      a0 = fmaf(qv.w, s3v.x, a0); a1 = fmaf(qv.w, s3v.y, a1);
      a2 = fmaf(qv.w, s3v.z, a2); a3 = fmaf(qv.w, s3v.w, a3);
    }
    const float4 sq4 = *(const float4*)&sqS[s0];
    const float k0 = fmaf(-2.f, a0, sq4.x);
    const float k1 = fmaf(-2.f, a1, sq4.y);
    const float k2 = fmaf(-2.f, a2, sq4.z);
    const float k3 = fmaf(-2.f, a3, sq4.w);
    bool u;  // ascending index, strict < => first minimum per lane
    u = k0 < bk; bk = u ? k0 : bk; bi = u ? s0 : bi;
    u = k1 < bk; bk = u ? k1 : bk; bi = u ? (s0 + 1) : bi;
    u = k2 < bk; bk = u ? k2 : bk; bi = u ? (s0 + 2) : bi;
    u = k3 < bk; bk = u ? k3 : bk; bi = u ? (s0 + 3) : bi;
  }
  // Cross-lane lexicographic argmin on exact keys => first-index semantics.
#pragma unroll
  for (int d = 1; d < 64; d <<= 1) {
    const float ok = __shfl_xor(bk, d, 64);
    const int oi = __shfl_xor(bi, d, 64);
    const bool u = (ok < bk) || (ok == bk && oi < bi);
    bk = u ? ok : bk;
    bi = u ? oi : bi;
  }
  // Label: one-hot rows exact {0,1}; first 1 == np.argmax.
  const float ov = onehot[(size_t)bi * 64 + lane];
  const unsigned long long lm = __ballot(ov > 0.5f);
  const int label = __ffsll((long long)lm) - 1;
  out[(size_t)q * 64 + lane] = (lane == label) ? 1.0f : 0.0f;
}

// ---------------------------------------------------------------------------
extern "C" void kernel_launch(void* const* d_in, const int* in_sizes, int n_in,
                              void* d_out, int out_size, void* d_ws, size_t ws_size,
                              hipStream_t stream) {
  const float* S = (const float*)d_in[0];   // [16384][64]
  const float* Q = (const float*)d_in[1];   // [16384][64]
  const float* OH = (const float*)d_in[2];  // [16384][64]
  float* out = (float*)d_out;

  char* ws = (char*)d_ws;
  ushort* Sh = (ushort*)ws;                                  // 2 MB
  ushort* Qh = (ushort*)(ws + (2u << 20));                   // 2 MB
  float* S_T = (float*)(ws + (4u << 20));                    // 4 MB
  float* sqS = (float*)(ws + (8u << 20));                    // 64 KB
  float* bmin = (float*)(ws + (8u << 20) + (64u << 10));     // 4 MB

  k_split<<<dim3(2048), 256, 0, stream>>>(S, Q, Sh, Qh);
  k_transpose_sq<<<dim3(NTOT / 64), 256, 0, stream>>>(S, S_T, sqS);
  k_phaseA<<<dim3(NTOT / 64, 8), 256, 0, stream>>>(Sh, Qh, sqS, bmin);
  k_phaseB<<<dim3(NTOT / 4), 256, 0, stream>>>(S_T, Q, sqS, bmin, OH, out);
  (void)in_sizes; (void)n_in; (void)out_size; (void)ws_size;
}